// Round 1
// baseline (279.385 us; speedup 1.0000x reference)
//
#include <hip/hip_runtime.h>

// Overlap-add, gather formulation, 16 output samples per thread.
// Geometry fixed by setup_inputs(): B=32, NF=4000, FS=320, shift=160.
// sig_length = (NF-1)*shift + FS = 640160.
//
// Output sample t is covered by frames f with t - f*shift in [0, FS):
//   f = q = t/shift (offset r = t%shift)   if q <= NF-1
//   f = q-1         (offset r + shift)     if q >= 1
// Overlap count = 2 in the interior, 1 for t < shift and t >= NF*shift.
//
// Key fact: SHIFT % 16 == 0, so a 16-aligned run of 16 consecutive output
// samples lies entirely inside one half-window -> a single (q, r) pair per
// thread, 4 independent float4 loads per input stream (4x MLP vs the
// 1-float4-per-thread version), and 1/4 the integer div + branch work.

constexpr int B       = 32;
constexpr int NF      = 4000;
constexpr int FS      = 320;
constexpr int SHIFT   = 160;
constexpr int SIG_LEN = (NF - 1) * SHIFT + FS;   // 640160
constexpr int CH      = 16;                      // output samples per thread
constexpr int CH_PER_B = SIG_LEN / CH;           // 40010 (exact: 640160 = 16*40010)
constexpr int TOTAL    = B * CH_PER_B;           // 1,280,320 threads

typedef float f32x4 __attribute__((ext_vector_type(4)));

__global__ __launch_bounds__(256)
void ola_gather16(const float* __restrict__ in, float* __restrict__ out) {
    const int idx = blockIdx.x * 256 + threadIdx.x;
    if (idx >= TOTAL) return;

    const int b = idx / CH_PER_B;
    const int c = idx - b * CH_PER_B;     // 16-sample chunk index within batch
    const int t = c * CH;                 // first of 16 consecutive output samples
    const int q = c / (SHIFT / CH);       // == t / SHIFT (candidate frame, 0..NF)
    const int r = t - q * SHIFT;          // offset within frame q; 16-aligned, <= 144

    const float* __restrict__ inb = in + (long long)b * ((long long)NF * FS);

    f32x4 o0, o1, o2, o3;
    if (q >= 1 && q < NF) {
        // Interior: frame q at offset r, frame q-1 at offset r+SHIFT; count = 2.
        const f32x4* __restrict__ p0 =
            (const f32x4*)(inb + (long long)q * FS + r);
        const f32x4* __restrict__ p1 =
            (const f32x4*)(inb + (long long)(q - 1) * FS + r + SHIFT);
        const f32x4 a0 = p0[0], a1 = p0[1], a2 = p0[2], a3 = p0[3];
        const f32x4 b0 = p1[0], b1 = p1[1], b2 = p1[2], b3 = p1[3];
        o0 = 0.5f * (a0 + b0);
        o1 = 0.5f * (a1 + b1);
        o2 = 0.5f * (a2 + b2);
        o3 = 0.5f * (a3 + b3);
    } else if (q == 0) {
        // Leading half-window: only frame 0 contributes; count = 1.
        const f32x4* __restrict__ p0 = (const f32x4*)(inb + r);
        o0 = p0[0]; o1 = p0[1]; o2 = p0[2]; o3 = p0[3];
    } else {
        // Trailing half-window (q == NF): only frame NF-1 contributes; count = 1.
        const f32x4* __restrict__ p1 =
            (const f32x4*)(inb + (long long)(NF - 1) * FS + r + SHIFT);
        o0 = p1[0]; o1 = p1[1]; o2 = p1[2]; o3 = p1[3];
    }

    // Output is never re-read: nontemporal stores (early L2 eviction).
    f32x4* __restrict__ po = (f32x4*)(out + (long long)b * SIG_LEN + t);
    __builtin_nontemporal_store(o0, po + 0);
    __builtin_nontemporal_store(o1, po + 1);
    __builtin_nontemporal_store(o2, po + 2);
    __builtin_nontemporal_store(o3, po + 3);
}

extern "C" void kernel_launch(void* const* d_in, const int* in_sizes, int n_in,
                              void* d_out, int out_size, void* d_ws, size_t ws_size,
                              hipStream_t stream) {
    const float* in = (const float*)d_in[0];
    float* out = (float*)d_out;

    constexpr int block  = 256;
    constexpr int blocks = (TOTAL + block - 1) / block;  // 5002

    ola_gather16<<<blocks, block, 0, stream>>>(in, out);
}

// Round 2
// 252.444 us; speedup vs baseline: 1.1067x; 1.1067x over previous
//
#include <hip/hip_runtime.h>

// Overlap-add, gather formulation, ILP=4 with strict per-instruction coalescing.
// Geometry fixed by setup_inputs(): B=32, NF=4000, FS=320, shift=160.
// sig_length = (NF-1)*shift + FS = 640160.
//
// Output sample t is covered by frames f with t - f*shift in [0, FS):
//   f = q = t/shift (offset r = t%shift)   if q <= NF-1
//   f = q-1         (offset r + shift)     if q >= 1
// Overlap count = 2 in the interior, 1 for t < shift and t >= NF*shift.
//
// Lesson from round 1 (measured): per-thread CONSECUTIVE 64B chunks break
// per-instruction coalescing (each store instr = 64 lanes x 16B at stride 64B
// -> partial-line writes -> 1.55x HBM write amplification, kernel 52->105us).
// Correct layout: lane i <-> consecutive float4 group (1KB/wave/instr, full
// lines). ILP comes from 4 pieces per thread spaced NTHREADS apart instead.

constexpr int B       = 32;
constexpr int NF      = 4000;
constexpr int FS      = 320;
constexpr int SHIFT   = 160;
constexpr int SIG_LEN = (NF - 1) * SHIFT + FS;   // 640160
constexpr int GROUPS_PER_B = SIG_LEN / 4;        // 160040 float4 groups per batch
constexpr int TOTAL_G  = B * GROUPS_PER_B;       // 5,121,280 float4 groups
constexpr int PIECES   = 4;
constexpr int NTHREADS = TOTAL_G / PIECES;       // 1,280,320 (exact)
constexpr int QDIV     = SHIFT / 4;              // 40 groups per shift

typedef float f32x4 __attribute__((ext_vector_type(4)));

__global__ __launch_bounds__(256)
void ola_gather_ilp4(const float* __restrict__ in, float* __restrict__ out) {
    const int idx = blockIdx.x * 256 + threadIdx.x;
    if (idx >= NTHREADS) return;

    f32x4     res[PIECES];
    long long op[PIECES];

    #pragma unroll
    for (int p = 0; p < PIECES; ++p) {
        const int g   = idx + p * NTHREADS;        // float4 group id, < TOTAL_G
        const int b   = g / GROUPS_PER_B;          // batch (magic-mul)
        const int rem = g - b * GROUPS_PER_B;      // group within batch
        const int q   = rem / QDIV;                // candidate frame, 0..NF
        const int r   = (rem - q * QDIV) * 4;      // offset in frame q, 4-aligned

        const float* __restrict__ inb = in + (long long)b * ((long long)NF * FS);

        f32x4 acc = {0.f, 0.f, 0.f, 0.f};
        int cnt = 0;
        if (q < NF) {                              // frame q, offset r
            acc += *(const f32x4*)(inb + q * FS + r);
            ++cnt;
        }
        if (q >= 1) {                              // frame q-1, offset r+SHIFT
            acc += *(const f32x4*)(inb + (q - 1) * FS + r + SHIFT);
            ++cnt;
        }
        res[p] = acc * ((cnt == 2) ? 0.5f : 1.0f);
        op[p]  = (long long)b * SIG_LEN + (long long)rem * 4;
    }

    // Full-line coalesced nontemporal stores (output never re-read).
    #pragma unroll
    for (int p = 0; p < PIECES; ++p) {
        __builtin_nontemporal_store(res[p], (f32x4*)(out + op[p]));
    }
}

extern "C" void kernel_launch(void* const* d_in, const int* in_sizes, int n_in,
                              void* d_out, int out_size, void* d_ws, size_t ws_size,
                              hipStream_t stream) {
    const float* in = (const float*)d_in[0];
    float* out = (float*)d_out;

    constexpr int block  = 256;
    constexpr int blocks = (NTHREADS + block - 1) / block;  // 5002

    ola_gather_ilp4<<<blocks, block, 0, stream>>>(in, out);
}

// Round 3
// 248.763 us; speedup vs baseline: 1.1231x; 1.0148x over previous
//
#include <hip/hip_runtime.h>

// Overlap-add, gather formulation. Round-0 structure (best measured: 247.2us
// total) + nontemporal stores as the single changed variable.
//
// Geometry fixed by setup_inputs(): B=32, NF=4000, FS=320, shift=160.
// sig_length = (NF-1)*shift + FS = 640160.
// Output sample t is covered by frames f with t - f*shift in [0, FS):
//   f = q = t/shift (offset r = t%shift)   if q <= NF-1
//   f = q-1         (offset r + shift)     if q >= 1
// Overlap count = 2 in the interior, 1 for t < shift and t >= NF*shift.
//
// Measured lessons carried forward:
//  - r1: per-thread consecutive 64B chunks -> 64 lanes x 16B @ stride 64
//    = partial-line stores -> 1.55x write amplification, kernel 52->105us.
//    Lane i MUST own the i-th consecutive float4 group (1KB/wave full lines).
//  - r2: ILP4 (pieces spaced NTHREADS apart) + NT stores = ~57us slice,
//    worse than plain r0 (~52us). Reverting the ILP split; keeping NT only.
//  - VALUBusy ~1.4%: integer div/branch cost is irrelevant; do NOT trade
//    memory pattern for address-math savings.

constexpr int B       = 32;
constexpr int NF      = 4000;
constexpr int FS      = 320;
constexpr int SHIFT   = 160;
constexpr int SIG_LEN = (NF - 1) * SHIFT + FS;   // 640160
constexpr int GROUPS_PER_B = SIG_LEN / 4;        // 160040 float4 groups per batch
constexpr int TOTAL_G = B * GROUPS_PER_B;        // 5,121,280 float4 groups
constexpr int QDIV    = SHIFT / 4;               // 40 groups per shift

typedef float f32x4 __attribute__((ext_vector_type(4)));

__global__ __launch_bounds__(256)
void ola_gather_nt(const float* __restrict__ in, float* __restrict__ out) {
    const int idx = blockIdx.x * 256 + threadIdx.x;
    if (idx >= TOTAL_G) return;

    // All offsets fit int32: b*NF*FS <= 39.7M, b*SIG_LEN + t <= 20.5M.
    const int b = idx / GROUPS_PER_B;            // batch (magic-mul)
    const int g = idx - b * GROUPS_PER_B;        // float4 group within batch
    const int t = g * 4;                         // first of 4 output samples
    const int q = g / QDIV;                      // candidate frame, 0..NF
    const int r = t - q * SHIFT;                 // offset in frame q, 4-aligned

    const float* __restrict__ inb = in + b * (NF * FS);

    f32x4 acc = {0.f, 0.f, 0.f, 0.f};
    int cnt = 0;
    if (q < NF) {                                // frame q, offset r
        acc += *(const f32x4*)(inb + q * FS + r);
        ++cnt;
    }
    if (q >= 1) {                                // frame q-1, offset r+SHIFT
        acc += *(const f32x4*)(inb + (q - 1) * FS + r + SHIFT);
        ++cnt;
    }
    const f32x4 o = acc * ((cnt == 2) ? 0.5f : 1.0f);

    // Single changed variable vs round 0: nontemporal store. Output is never
    // re-read; keeping it out of L3 preserves input residency (r1 showed
    // FETCH=80MB of a 164MB input -> L3 holds ~half the input across iters).
    __builtin_nontemporal_store(o, (f32x4*)(out + b * SIG_LEN + t));
}

extern "C" void kernel_launch(void* const* d_in, const int* in_sizes, int n_in,
                              void* d_out, int out_size, void* d_ws, size_t ws_size,
                              hipStream_t stream) {
    const float* in = (const float*)d_in[0];
    float* out = (float*)d_out;

    constexpr int block  = 256;
    constexpr int blocks = (TOTAL_G + block - 1) / block;  // 20005

    ola_gather_nt<<<blocks, block, 0, stream>>>(in, out);
}